// Round 2
// baseline (341.212 us; speedup 1.0000x reference)
//
#include <hip/hip_runtime.h>

// NTuple approximator evaluation:
// out[b] = sum_{s=0}^{31} weights[table_ids[s], base16(boards[b, sym_coords[s,:]])]
// B = 65536 boards, 32 symmetries, 6 coords each, weights = 4 x 16^6 fp32 (256 MB).
//
// R1: 1 thread/board = 1024 waves = 1 wave/SIMD -> latency-bound (339 us vs
//     ~40 us gather-BW floor).
// R2: 8 threads/board, 4 gathers each -> 8192 waves = 8 waves/SIMD.
//     Intra-wave shfl_xor reduction over the 8 lanes of each board.

static constexpr int NSYM = 32;
static constexpr int TLEN = 6;
static constexpr int TPB_BOARD = 8;               // threads per board
static constexpr int SYMS_PER_T = NSYM / TPB_BOARD;  // 4

__global__ __launch_bounds__(256) void ntuple_eval_kernel(
    const int* __restrict__ boards,
    const float* __restrict__ weights,
    const int* __restrict__ sym_coords,
    const int* __restrict__ table_ids,
    float* __restrict__ out, int B)
{
    __shared__ int s_coords[NSYM * TLEN];
    __shared__ int s_base[NSYM];

    const int t = threadIdx.x;
    if (t < NSYM * TLEN) s_coords[t] = sym_coords[t];
    if (t < NSYM)        s_base[t]   = table_ids[t] << 24;  // * 16^6
    __syncthreads();

    const int g = blockIdx.x * blockDim.x + t;
    const int b = g >> 3;            // board index
    const int chunk = g & 7;         // which 4 symmetries
    if (b >= B) return;

    // 8 lanes of the same board load the same 64 B -> coalesced/broadcast.
    const int4* bp = reinterpret_cast<const int4*>(boards + (size_t)b * 16);
    const int4 r0 = bp[0], r1 = bp[1], r2 = bp[2], r3 = bp[3];

    const int c[16] = {r0.x, r0.y, r0.z, r0.w,
                       r1.x, r1.y, r1.z, r1.w,
                       r2.x, r2.y, r2.z, r2.w,
                       r3.x, r3.y, r3.z, r3.w};
    unsigned long long packed = 0ull;
#pragma unroll
    for (int i = 0; i < 16; ++i)
        packed |= (unsigned long long)((unsigned)c[i] & 15u) << (4 * i);

    float acc = 0.0f;
#pragma unroll
    for (int k = 0; k < SYMS_PER_T; ++k) {
        const int s = chunk * SYMS_PER_T + k;
        int feat = 0;
#pragma unroll
        for (int j = 0; j < TLEN; ++j) {
            const int cc = s_coords[s * TLEN + j];   // LDS broadcast (8-lane groups uniform)
            feat = (feat << 4) | (int)((packed >> (cc << 2)) & 15ull);
        }
        acc += weights[(size_t)(s_base[s] + feat)];  // independent gathers
    }

    // Reduce the 8 lanes of this board (lanes are contiguous within the wave).
    acc += __shfl_xor(acc, 1, 8);
    acc += __shfl_xor(acc, 2, 8);
    acc += __shfl_xor(acc, 4, 8);
    if (chunk == 0) out[b] = acc;
}

extern "C" void kernel_launch(void* const* d_in, const int* in_sizes, int n_in,
                              void* d_out, int out_size, void* d_ws, size_t ws_size,
                              hipStream_t stream) {
    const int*   boards     = (const int*)d_in[0];
    const float* weights    = (const float*)d_in[1];
    const int*   sym_coords = (const int*)d_in[2];
    const int*   table_ids  = (const int*)d_in[3];
    float*       out        = (float*)d_out;

    const int B = in_sizes[0] / 16;
    const int block = 256;
    const int total = B * TPB_BOARD;
    const int grid = (total + block - 1) / block;
    ntuple_eval_kernel<<<grid, block, 0, stream>>>(boards, weights, sym_coords,
                                                   table_ids, out, B);
}